// Round 7
// baseline (217.336 us; speedup 1.0000x reference)
//
#include <hip/hip_runtime.h>

// VertexDistExtract3D: out[b,k,p] = (R(q_b) * verts[b,k] + pos_b) . dirs[p]
// Folded: out[b,k,p] = verts[b,k] . (R^T dirs[p]) + pos_b . dirs[p]
// B=131072, K=64, P=4, D=199. Memory-bound: ~104 MB read-once + ~134 MB
// write-once => non-temporal on both streams; header via scalar path.
// Grid-stride @ 2048 blocks (8 wg/CU) to amortize launch ramp.

constexpr int B = 131072;
constexpr int K = 64;
constexpr int P = 4;
constexpr int D = 7 + 3 * K; // 199

struct F3 { float a, b, c; };                              // 12B, align 4
typedef float f32x4 __attribute__((ext_vector_type(4)));   // clang vector: nontemporal-store-able

__global__ __launch_bounds__(256) void vde_kernel(const float* __restrict__ x,
                                                  const float* __restrict__ dirs,
                                                  float* __restrict__ out) {
    // dirs is tiny + thread-invariant: hoist to registers once (s_load).
    float d0v[P], d1v[P], d2v[P];
#pragma unroll
    for (int p = 0; p < P; ++p) {
        d0v[p] = dirs[p * 3 + 0];
        d1v[p] = dirs[p * 3 + 1];
        d2v[p] = dirs[p * 3 + 2];
    }

    const int lane = threadIdx.x & 63;          // = k
    const int nthreads = gridDim.x * blockDim.x;
    const int total = B * K;

    for (int tid = blockIdx.x * blockDim.x + threadIdx.x; tid < total;
         tid += nthreads) {
        const int b = tid >> 6;                 // wave-uniform

        const int rowoff = __builtin_amdgcn_readfirstlane(b * D);
        const float* row = x + rowoff;

        // Header (wave-uniform, scalar-cache path)
        const float px = row[0], py = row[1], pz = row[2];
        const float qw = row[3], qx = row[4], qy = row[5], qz = row[6];

        const float xx = qx * qx, yy = qy * qy, zz = qz * qz;
        const float xy = qx * qy, xz = qx * qz, yz = qy * qz;
        const float wx = qw * qx, wy = qw * qy, wz = qw * qz;

        const float r00 = 1.0f - 2.0f * (yy + zz);
        const float r01 = 2.0f * (xy - wz);
        const float r02 = 2.0f * (xz + wy);
        const float r10 = 2.0f * (xy + wz);
        const float r11 = 1.0f - 2.0f * (xx + zz);
        const float r12 = 2.0f * (yz - wx);
        const float r20 = 2.0f * (xz - wy);
        const float r21 = 2.0f * (yz + wx);
        const float r22 = 1.0f - 2.0f * (xx + yy);

        // This lane's vertex: 12B non-temporal load (read-once stream)
        const F3* vp = reinterpret_cast<const F3*>(row + 7 + 3 * lane);
        F3 v;
        v.a = __builtin_nontemporal_load(&vp->a);
        v.b = __builtin_nontemporal_load(&vp->b);
        v.c = __builtin_nontemporal_load(&vp->c);

        f32x4 o;
#pragma unroll
        for (int p = 0; p < P; ++p) {
            const float m0 = d0v[p] * r00 + d1v[p] * r10 + d2v[p] * r20;
            const float m1 = d0v[p] * r01 + d1v[p] * r11 + d2v[p] * r21;
            const float m2 = d0v[p] * r02 + d1v[p] * r12 + d2v[p] * r22;
            const float c  = d0v[p] * px + d1v[p] * py + d2v[p] * pz;
            o[p] = v.a * m0 + v.b * m1 + v.c * m2 + c;
        }

        // Coalesced 16B non-temporal store (write-once stream)
        f32x4* outp = reinterpret_cast<f32x4*>(out + (size_t)tid * 4);
        __builtin_nontemporal_store(o, outp);
    }
}

extern "C" void kernel_launch(void* const* d_in, const int* in_sizes, int n_in,
                              void* d_out, int out_size, void* d_ws, size_t ws_size,
                              hipStream_t stream) {
    const float* x    = (const float*)d_in[0];
    const float* dirs = (const float*)d_in[1];
    float* out        = (float*)d_out;

    const int block = 256;
    const int grid = 2048;   // 8 wg/CU, grid-stride covers 8.4M threads
    vde_kernel<<<grid, block, 0, stream>>>(x, dirs, out);
}